// Round 8
// baseline (622.808 us; speedup 1.0000x reference)
//
#include <hip/hip_runtime.h>

// Problem constants (fixed by reference)
#define NN 50000      // nodes
#define NE 800000     // edges
#define DD 256        // node feat dim
#define GFEAT 200     // graph feat dim
#define NG 512        // graphs

typedef __bf16 bf16;
typedef bf16 bf16x4 __attribute__((ext_vector_type(4)));
typedef bf16 bf16x8 __attribute__((ext_vector_type(8)));
typedef float f32x4 __attribute__((ext_vector_type(4)));

// async global->LDS, 16B per lane. HW dest = wave-uniform base + lane*16.
__device__ __forceinline__ void gl_lds16(const bf16* g, bf16* l) {
    __builtin_amdgcn_global_load_lds(
        (const __attribute__((address_space(1))) uint32_t*)(g),
        (__attribute__((address_space(3))) uint32_t*)(l), 16, 0, 0);
}

// BK=64 LDS tile [R][64]; 16B chunk c holds global chunk c^((row>>1)&7)
__device__ __forceinline__ bf16x8 frag_ld64(const bf16* s, int R, int C) {
    return *(const bf16x8*)&s[R * 64 + ((C ^ ((R >> 1) & 7)) << 3)];
}

#define EPI_STRIDE 136   // bf16 elems; 272 B row stride (16B-aligned, bank-shift 4/row)

// CSR params
#define NBKT   128
#define NPB    391            // ceil(NN / NBKT); 128*391 = 50048
#define NCHUNK 256
#define CE     ((NE + NCHUNK - 1) / NCHUNK)   // 3125 edges per chunk

// fat-kernel split of the 1600 fusedconv blocks
#define NF1 600
#define NF2 1000

// ---------------------------------------------------------------------------
// device roles for the fat kernels (512 threads each)
// ---------------------------------------------------------------------------

// weight transpose-convert: fp32 [256][N] -> bf16 [n][k], 64x64 LDS tile
__device__ void d_convw(int bb, const float* const* ws, const int* Ns,
                        bf16* out_base, char* sm) {
    const int m = bb >> 4, tile = bb & 15;
    const int k0 = (tile >> 2) * 64, n0 = (tile & 3) * 64;
    const float* in = ws[m];
    const int N = Ns[m];
    const int t = threadIdx.x;
    float (*ts)[65] = (float(*)[65])sm;
#pragma unroll
    for (int r = 0; r < 8; r++) {
        int dk = r * 8 + (t >> 6), dn = t & 63;
        int n = n0 + dn;
        ts[dk][dn] = (n < N) ? in[(k0 + dk) * N + n] : 0.f;
    }
    __syncthreads();
#pragma unroll
    for (int r = 0; r < 8; r++) {
        int dn = r * 8 + (t >> 6), dk = t & 63;
        out_base[(size_t)m * 65536 + (size_t)(n0 + dn) * 256 + k0 + dk] = (bf16)ts[dk][dn];
    }
}

__device__ void d_hist(int hb, const int* d0, const int* d1,
                       int* cnt0, int* cnt1, char* sm) {
    const int branch = hb >> 8, blk = hb & 255;
    const int* dst = branch ? d1 : d0;
    int* cnt = branch ? cnt1 : cnt0;
    int* hist = (int*)sm;
    const int t = threadIdx.x;
    if (t < NBKT) hist[t] = 0;
    __syncthreads();
    const int e0 = blk * CE;
    const int e1 = (e0 + CE < NE) ? e0 + CE : NE;
    for (int e = e0 + t; e < e1; e += 512)
        atomicAdd(&hist[dst[e] / NPB], 1);
    __syncthreads();
    if (t < NBKT) cnt[t * NCHUNK + blk] = hist[t];   // bucket-major
}

__device__ void d_partition(int pb, const int* sA, const int* sB,
                            const int* d0, const int* d1,
                            const int* cnt0, const int* cnt1,
                            int2* eb0, int2* eb1, char* sm) {
    const int branch = pb >> 8, blk = pb & 255;
    const int* src = branch ? sB : sA;
    const int* dst = branch ? d1 : d0;
    const int* cnt = branch ? cnt1 : cnt0;
    int2* eb = branch ? eb1 : eb0;
    int* cur = (int*)sm;
    const int t = threadIdx.x;
    if (t < NBKT) cur[t] = cnt[t * NCHUNK + blk];
    __syncthreads();
    const int e0 = blk * CE;
    const int e1 = (e0 + CE < NE) ? e0 + CE : NE;
    for (int e = e0 + t; e < e1; e += 512) {
        int d = dst[e], s = src[e];
        int pos = atomicAdd(&cur[d / NPB], 1);   // LDS atomic, disjoint ranges
        eb[pos] = make_int2(s, d);
    }
}

__device__ void d_sort(int sb, const int* cnt0, const int* cnt1,
                       const int2* eb0, const int2* eb1,
                       int* offs0, int* offs1, int* csr0, int* csr1, char* sm) {
    const int branch = sb >> 7, b = sb & 127;
    const int* cnt = branch ? cnt1 : cnt0;
    const int2* eb = branch ? eb1 : eb0;
    int* offs = branch ? offs1 : offs0;
    int* csr = branch ? csr1 : csr0;
    const int lo = b * NPB;
    const int ncnt = (NN - lo < NPB) ? (NN - lo) : NPB;
    const int beg = cnt[b * NCHUNK];
    const int end = (b == NBKT - 1) ? NE : cnt[(b + 1) * NCHUNK];
    const int t = threadIdx.x;

    int* hist = (int*)sm;            // 400 ints
    int* s = ((int*)sm) + 400;       // 512 ints
    if (t < NPB) hist[t] = 0;
    __syncthreads();
    for (int i = beg + t; i < end; i += 512)
        atomicAdd(&hist[eb[i].y - lo], 1);
    __syncthreads();

    int h = (t < NPB) ? hist[t] : 0;
    s[t] = h;
    __syncthreads();
    for (int off = 1; off < 512; off <<= 1) {
        int a = (t >= off) ? s[t - off] : 0;
        __syncthreads();
        s[t] += a;
        __syncthreads();
    }
    int excl = s[t] - h;
    __syncthreads();
    if (t < NPB) hist[t] = excl;
    if (t < ncnt) offs[lo + t] = beg + excl;
    __syncthreads();

    for (int i = beg + t; i < end; i += 512) {
        int2 v = eb[i];
        int pos = atomicAdd(&hist[v.y - lo], 1);
        csr[beg + pos] = v.x;
    }
}

// fusedconv GEMM block (R6 structure): 256x128 tile, 512 thr, BK=64, K=256.
// A = fp32 X reg-staged + cvt; B via gl_lds. f in [0,1600): br=f&1, lid=f>>1.
__device__ void d_fusedconv(int f, const float* X0, const float* X1,
                            const bf16* Bt2_0, const bf16* Bt2_1,
                            const float* bh0, const float* bh1,
                            bf16* lo0, bf16* lo1, bf16* hi0, bf16* hi1,
                            int M, char* smc) {
    const int br = f & 1, lid = f >> 1;
    const int r8 = lid & 7, cc = (lid >> 3) & 3, g = lid >> 5;
    const int row_blk = g * 8 + r8;
    if (row_blk * 256 >= M) return;
    const float* Xf = br ? X1 : X0;
    const bf16* Bt2 = br ? Bt2_1 : Bt2_0;
    const float* bias_hi = br ? bh1 : bh0;
    bf16* out_lo = br ? lo1 : lo0;
    bf16* out_hi = br ? hi1 : hi0;

    bf16* smem = (bf16*)smc;
    bf16* As = smem;                 // 256x64 = 32KB
    bf16* Bs = smem + 16384;         // 128x64 = 16KB

    const int t    = threadIdx.x;
    const int lane = t & 63;
    const int w    = t >> 6;
    const int row0 = row_blk * 256;
    const int col0 = cc * 128;       // 0..384

    f32x4 acc[4][4] = {};
    const int wm = (w >> 1) * 64, wn = (w & 1) * 64;
    const int fm = lane & 15, fC = lane >> 4;

    for (int k0 = 0; k0 < 256; k0 += 64) {
#pragma unroll
        for (int r = 0; r < 2; r++) {            // Bs async first
            int flat = r * 512 + t;
            int fr = flat >> 3, fc = flat & 7;
            int fcg = fc ^ ((fr >> 1) & 7);
            int brow = col0 + fr;
            gl_lds16(&Bt2[(size_t)brow * 256 + k0 + fcg * 8], &Bs[flat * 8]);
        }
#pragma unroll
        for (int r = 0; r < 4; r++) {            // As: fp32 load + cvt + swizzled write
            int flat = r * 512 + t;
            int fr = flat >> 3, fc = flat & 7;
            int arow = row0 + fr;
            if (arow > M - 1) arow = M - 1;
            const float* gsrc = &Xf[(size_t)arow * 256 + k0 + fc * 8];
            float4 u0 = *(const float4*)gsrc;
            float4 u1 = *(const float4*)(gsrc + 4);
            bf16x8 o;
            o[0] = (bf16)u0.x; o[1] = (bf16)u0.y; o[2] = (bf16)u0.z; o[3] = (bf16)u0.w;
            o[4] = (bf16)u1.x; o[5] = (bf16)u1.y; o[6] = (bf16)u1.z; o[7] = (bf16)u1.w;
            *(bf16x8*)&As[fr * 64 + ((fc ^ ((fr >> 1) & 7)) << 3)] = o;
        }
        __syncthreads();
#pragma unroll
        for (int s = 0; s < 2; s++) {
            bf16x8 af[4], bfr[4];
#pragma unroll
            for (int i = 0; i < 4; i++) af[i] = frag_ld64(As, wm + i * 16 + fm, s * 4 + fC);
#pragma unroll
            for (int i = 0; i < 4; i++) bfr[i] = frag_ld64(Bs, wn + i * 16 + fm, s * 4 + fC);
#pragma unroll
            for (int i = 0; i < 4; i++)
#pragma unroll
                for (int j = 0; j < 4; j++)
                    acc[i][j] = __builtin_amdgcn_mfma_f32_16x16x32_bf16(af[i], bfr[j], acc[i][j], 0, 0, 0);
        }
        __syncthreads();
    }

    const bool hi = (col0 >= 256);
    bf16* out = hi ? out_hi : out_lo;
    const int cb = hi ? col0 - 256 : col0;

    float bv[4];
#pragma unroll
    for (int j = 0; j < 4; j++) {
        int col = cb + wn + fm + j * 16;
        bv[j] = hi ? bias_hi[col] : 0.f;
    }

#pragma unroll
    for (int p = 0; p < 4; p++) {
        if ((w >> 1) == p) {
#pragma unroll
            for (int i = 0; i < 4; i++)
#pragma unroll
                for (int j = 0; j < 4; j++)
#pragma unroll
                    for (int r2 = 0; r2 < 4; r2++) {
                        int rl = i * 16 + (lane >> 4) * 4 + r2;
                        int cl = wn + fm + j * 16;
                        float v = acc[i][j][r2] + bv[j];
                        if (hi) v = fmaxf(v, 0.f);
                        smem[rl * EPI_STRIDE + cl] = (bf16)v;
                    }
        }
        __syncthreads();
#pragma unroll
        for (int q = 0; q < 2; q++) {
            int flat = q * 512 + t;
            int rl = flat >> 4, seg = flat & 15;
            int grow = row0 + p * 64 + rl;
            if (grow < M)
                *(bf16x8*)&out[(size_t)grow * 256 + cb + seg * 8] =
                    *(const bf16x8*)&smem[rl * EPI_STRIDE + seg * 8];
        }
        __syncthreads();
    }
}

// ---------------------------------------------------------------------------
// fat kernels
// ---------------------------------------------------------------------------
// L1: zero_G [0,400) | conv_w [400,528) | csr_hist [528,1040)
__global__ __launch_bounds__(512) void k_prep(
    float* __restrict__ G1, float* __restrict__ G2,
    const float* w0, const float* w1, const float* w2, const float* w3,
    const float* w4, const float* w5, const float* w6, const float* w7,
    bf16* __restrict__ Wbase,
    const int* __restrict__ d0, const int* __restrict__ d1,
    int* __restrict__ cnt0, int* __restrict__ cnt1) {
    __shared__ __align__(16) char sm[16704];
    const int b = blockIdx.x;
    if (b < 400) {
        int i = b * 512 + threadIdx.x;
        if (i < NG * GFEAT) G1[i] = 0.f;
        else if (i < 2 * NG * GFEAT) G2[i - NG * GFEAT] = 0.f;
    } else if (b < 528) {
        const float* ws[8] = {w0, w1, w2, w3, w4, w5, w6, w7};
        const int Ns[8] = {DD, DD, DD, GFEAT, DD, DD, DD, GFEAT};
        d_convw(b - 400, ws, Ns, Wbase, sm);
    } else {
        d_hist(b - 528, d0, d1, cnt0, cnt1, sm);
    }
}

__global__ __launch_bounds__(1024) void csr_scan_kernel(
    int* __restrict__ cnt0, int* __restrict__ cnt1,
    int* __restrict__ offs0, int* __restrict__ offs1) {
    int* cnt = blockIdx.y ? cnt1 : cnt0;
    const int t = threadIdx.x;
    const int PER = (NBKT * NCHUNK) / 1024;   // 32
    int v[PER];
    int sum = 0;
    const int base = t * PER;
#pragma unroll
    for (int i = 0; i < PER; i += 4) {
        int4 q = *(const int4*)&cnt[base + i];
        v[i] = q.x; v[i + 1] = q.y; v[i + 2] = q.z; v[i + 3] = q.w;
        sum += q.x + q.y + q.z + q.w;
    }
    __shared__ int s[1024];
    s[t] = sum;
    __syncthreads();
    for (int off = 1; off < 1024; off <<= 1) {
        int a = (t >= off) ? s[t - off] : 0;
        __syncthreads();
        s[t] += a;
        __syncthreads();
    }
    int run = s[t] - sum;
#pragma unroll
    for (int i = 0; i < PER; i++) { int c = v[i]; cnt[base + i] = run; run += c; }
    if (t == 0) (blockIdx.y ? offs1 : offs0)[NN] = NE;
}

// L3: csr_partition [0,512) | fusedconv f in [0,NF1)
__global__ __launch_bounds__(512) void k_part_gemm(
    const int* __restrict__ sA, const int* __restrict__ sB,
    const int* __restrict__ d0, const int* __restrict__ d1,
    const int* __restrict__ cnt0, const int* __restrict__ cnt1,
    int2* __restrict__ eb0, int2* __restrict__ eb1,
    const float* __restrict__ X0, const float* __restrict__ X1,
    const bf16* __restrict__ Bt2_0, const bf16* __restrict__ Bt2_1,
    const float* __restrict__ bh0, const float* __restrict__ bh1,
    bf16* __restrict__ lo0, bf16* __restrict__ lo1,
    bf16* __restrict__ hi0, bf16* __restrict__ hi1, int M) {
    __shared__ __align__(16) char sm[49152];
    const int b = blockIdx.x;
    if (b < 512) d_partition(b, sA, sB, d0, d1, cnt0, cnt1, eb0, eb1, sm);
    else d_fusedconv(b - 512, X0, X1, Bt2_0, Bt2_1, bh0, bh1, lo0, lo1, hi0, hi1, M, sm);
}

// L4: csr_bucket_sort [0,256) | fusedconv f in [NF1,1600)
__global__ __launch_bounds__(512) void k_sort_gemm(
    const int* __restrict__ cnt0, const int* __restrict__ cnt1,
    const int2* __restrict__ eb0, const int2* __restrict__ eb1,
    int* __restrict__ offs0, int* __restrict__ offs1,
    int* __restrict__ csr0, int* __restrict__ csr1,
    const float* __restrict__ X0, const float* __restrict__ X1,
    const bf16* __restrict__ Bt2_0, const bf16* __restrict__ Bt2_1,
    const float* __restrict__ bh0, const float* __restrict__ bh1,
    bf16* __restrict__ lo0, bf16* __restrict__ lo1,
    bf16* __restrict__ hi0, bf16* __restrict__ hi1, int M) {
    __shared__ __align__(16) char sm[49152];
    const int b = blockIdx.x;
    if (b < 256) d_sort(b, cnt0, cnt1, eb0, eb1, offs0, offs1, csr0, csr1, sm);
    else d_fusedconv(b - 256 + NF1, X0, X1, Bt2_0, Bt2_1, bh0, bh1,
                     lo0, lo1, hi0, hi1, M, sm);
}

// ---------------------------------------------------------------------------
// generic GEMM (R6): 256x128 tile, 512 thr, both branches, XCD-swizzled decode
// grid (25*16, 2)
// ---------------------------------------------------------------------------
__global__ __launch_bounds__(512) void mfma_gemm2_kernel(
    const bf16* __restrict__ A0, const bf16* __restrict__ A1,
    const bf16* __restrict__ Bt0, const bf16* __restrict__ Bt1,
    const float* __restrict__ bias0, const float* __restrict__ bias1,
    bf16* __restrict__ out0, bf16* __restrict__ out1,
    int M, int Nb, int do_relu) {
    const int lid = blockIdx.x;
    const int r8 = lid & 7, cc = (lid >> 3) & 1, g = lid >> 4;
    const int row_blk = g * 8 + r8;
    if (row_blk * 256 >= M) return;
    const bf16* A = blockIdx.y ? A1 : A0;
    const bf16* Bt = blockIdx.y ? Bt1 : Bt0;
    const float* bias = blockIdx.y ? bias1 : bias0;
    bf16* out = blockIdx.y ? out1 : out0;

    __shared__ bf16 smem[24576];       // As 16384 | Bs 8192
    bf16* As = smem;
    bf16* Bs = smem + 16384;

    const int t    = threadIdx.x;
    const int lane = t & 63;
    const int w    = t >> 6;
    const int row0 = row_blk * 256;
    const int col0 = cc * 128;

    f32x4 acc[4][4] = {};
    const int wm = (w >> 1) * 64, wn = (w & 1) * 64;
    const int fm = lane & 15, fC = lane >> 4;

    for (int k0 = 0; k0 < 256; k0 += 64) {
#pragma unroll
        for (int r = 0; r < 4; r++) {
            int flat = r * 512 + t;
            int fr = flat >> 3, fc = flat & 7;
            int fcg = fc ^ ((fr >> 1) & 7);
            int arow = row0 + fr;
            if (arow > M - 1) arow = M - 1;
            gl_lds16(&A[(size_t)arow * 256 + k0 + fcg * 8], &As[flat * 8]);
        }
#pragma unroll
        for (int r = 0; r < 2; r++) {
            int flat = r * 512 + t;
            int fr = flat >> 3, fc = flat & 7;
            int fcg = fc ^ ((fr >> 1) & 7);
            int brow = col0 + fr;
            gl_lds16(&Bt[(size_t)brow * 256 + k0 + fcg * 8], &Bs[flat * 8]);
        }
        __syncthreads();
#pragma unroll
        for (int s = 0; s < 2; s++) {
            bf16x8 af[4], bfr[4];
#pragma unroll
            for (int i = 0; i < 4; i++) af[i] = frag_ld64(As, wm + i * 16 + fm, s * 4 + fC);
#pragma unroll
            for (int i = 0; i < 4; i++) bfr[i] = frag_ld64(Bs, wn + i * 16 + fm, s * 4 + fC);
#pragma unroll
            for (int i = 0; i < 4; i++)
#pragma unroll
                for (int j = 0; j < 4; j++)
                    acc[i][j] = __builtin_amdgcn_mfma_f32_16x16x32_bf16(af[i], bfr[j], acc[i][j], 0, 0, 0);
        }
        __syncthreads();
    }

    float bv[4];
#pragma unroll
    for (int j = 0; j < 4; j++) {
        int col = col0 + wn + fm + j * 16;
        bv[j] = (col < Nb) ? bias[col] : 0.f;
    }

#pragma unroll
    for (int p = 0; p < 4; p++) {
        if ((w >> 1) == p) {
#pragma unroll
            for (int i = 0; i < 4; i++)
#pragma unroll
                for (int j = 0; j < 4; j++)
#pragma unroll
                    for (int r2 = 0; r2 < 4; r2++) {
                        int rl = i * 16 + (lane >> 4) * 4 + r2;
                        int cl = wn + fm + j * 16;
                        float v = acc[i][j][r2] + bv[j];
                        if (do_relu) v = fmaxf(v, 0.f);
                        smem[rl * EPI_STRIDE + cl] = (bf16)v;
                    }
        }
        __syncthreads();
#pragma unroll
        for (int q = 0; q < 2; q++) {
            int flat = q * 512 + t;
            int rl = flat >> 4, seg = flat & 15;
            int grow = row0 + p * 64 + rl;
            if (grow < M)
                *(bf16x8*)&out[(size_t)grow * 256 + col0 + seg * 8] =
                    *(const bf16x8*)&smem[rl * EPI_STRIDE + seg * 8];
        }
        __syncthreads();
    }
}

// Ro GEMM + per-graph segment reduce fused (R6). grid (25*16, 2).
__global__ __launch_bounds__(512) void mfma_gemm_reduce2_kernel(
    const bf16* __restrict__ A0, const bf16* __restrict__ A1,
    const bf16* __restrict__ Bt0, const bf16* __restrict__ Bt1,
    const float* __restrict__ bias0, const float* __restrict__ bias1,
    const int* __restrict__ gid0, const int* __restrict__ gid1,
    float* __restrict__ G0, float* __restrict__ G1, int M, int Nb) {
    const int lid = blockIdx.x;
    const int r8 = lid & 7, cc = (lid >> 3) & 1, g = lid >> 4;
    const int row_blk = g * 8 + r8;
    if (row_blk * 256 >= M) return;
    const bf16* A = blockIdx.y ? A1 : A0;
    const bf16* Bt = blockIdx.y ? Bt1 : Bt0;
    const float* bias = blockIdx.y ? bias1 : bias0;
    const int* gids = blockIdx.y ? gid1 : gid0;
    float* G = blockIdx.y ? G1 : G0;

    __shared__ bf16 smem[24576];
    bf16* As = smem;
    bf16* Bs = smem + 16384;

    const int t    = threadIdx.x;
    const int lane = t & 63;
    const int w    = t >> 6;
    const int row0 = row_blk * 256;
    const int col0 = cc * 128;

    f32x4 acc[4][4] = {};
    const int wm = (w >> 1) * 64, wn = (w & 1) * 64;
    const int fm = lane & 15, fC = lane >> 4;

    for (int k0 = 0; k0 < 256; k0 += 64) {
#pragma unroll
        for (int r = 0; r < 4; r++) {
            int flat = r * 512 + t;
            int fr = flat >> 3, fc = flat & 7;
            int fcg = fc ^ ((fr >> 1) & 7);
            int arow = row0 + fr;
            if (arow > M - 1) arow = M - 1;
            gl_lds16(&A[(size_t)arow * 256 + k0 + fcg * 8], &As[flat * 8]);
        }
#pragma unroll
        for (int r = 0; r < 2; r++) {
            int flat = r * 512 + t;
            int fr = flat >> 3, fc = flat & 7;
            int fcg = fc ^ ((fr >> 1) & 7);
            int brow = col0 + fr;
            gl_lds16(&Bt[(size_t)brow * 256 + k0 + fcg * 8], &Bs[flat * 8]);
        }
        __syncthreads();
#pragma unroll
        for (int s = 0; s < 2; s++) {
            bf16x8 af[4], bfr[4];
#pragma unroll
            for (int i = 0; i < 4; i++) af[i] = frag_ld64(As, wm + i * 16 + fm, s * 4 + fC);
#pragma unroll
            for (int i = 0; i < 4; i++) bfr[i] = frag_ld64(Bs, wn + i * 16 + fm, s * 4 + fC);
#pragma unroll
            for (int i = 0; i < 4; i++)
#pragma unroll
                for (int j = 0; j < 4; j++)
                    acc[i][j] = __builtin_amdgcn_mfma_f32_16x16x32_bf16(af[i], bfr[j], acc[i][j], 0, 0, 0);
        }
        __syncthreads();
    }

    float bv[4];
#pragma unroll
    for (int j = 0; j < 4; j++) {
        int col = col0 + wn + fm + j * 16;
        bv[j] = (col < Nb) ? bias[col] : 0.f;
    }

#pragma unroll
    for (int p = 0; p < 4; p++) {
        if ((w >> 1) == p) {
#pragma unroll
            for (int i = 0; i < 4; i++)
#pragma unroll
                for (int j = 0; j < 4; j++)
#pragma unroll
                    for (int r2 = 0; r2 < 4; r2++) {
                        int rl = i * 16 + (lane >> 4) * 4 + r2;
                        int cl = wn + fm + j * 16;
                        smem[rl * EPI_STRIDE + cl] = (bf16)(acc[i][j][r2] + bv[j]);
                    }
        }
        __syncthreads();
        {
            int c = t & 127, rh = t >> 7;        // rh 0..3, 16 rows each
            int colg = col0 + c;
            if (colg < Nb) {
                float run = 0.f;
                int gprev = -1;
                for (int r = 0; r < 16; r++) {
                    int grow = row0 + p * 64 + rh * 16 + r;
                    if (grow >= M) break;
                    int gg = gids[grow];
                    if (gg != gprev) {
                        if (gprev >= 0) atomicAdd(&G[(size_t)gprev * GFEAT + colg], run);
                        run = 0.f;
                        gprev = gg;
                    }
                    run += (float)smem[(rh * 16 + r) * EPI_STRIDE + c];
                }
                if (gprev >= 0) atomicAdd(&G[(size_t)gprev * GFEAT + colg], run);
            }
        }
        __syncthreads();
    }
}

// ---------------------------------------------------------------------------
// edge aggregation + combine, both branches (memory-system ceiling ~3.9 TB/s)
// ---------------------------------------------------------------------------
__global__ __launch_bounds__(256) void agg_combine2_kernel(
    const bf16* __restrict__ hW0, const bf16* __restrict__ hW1,
    const int* __restrict__ csr0, const int* __restrict__ csr1,
    const int* __restrict__ offs0, const int* __restrict__ offs1,
    const float* __restrict__ bias0, const float* __restrict__ bias1,
    const bf16* __restrict__ res0, const bf16* __restrict__ res1,
    bf16* __restrict__ H0, bf16* __restrict__ H1, int n_nodes) {
    const bf16* hW = blockIdx.y ? hW1 : hW0;
    const int* csr_src = blockIdx.y ? csr1 : csr0;
    const int* offsets = blockIdx.y ? offs1 : offs0;
    const float* bias = blockIdx.y ? bias1 : bias0;
    const bf16* res = blockIdx.y ? res1 : res0;
    bf16* H = blockIdx.y ? H1 : H0;

    int wave = threadIdx.x >> 6;
    int lane = threadIdx.x & 63;
    int node = blockIdx.x * 4 + wave;
    if (node >= n_nodes) return;
    int beg = offsets[node], end = offsets[node + 1];
    const int half = lane >> 5;
    const int fo   = (lane & 31) * 8;

    float acc[8] = {};
    int j = beg;
    for (; j + 6 + half < end; j += 8) {
        int s0 = csr_src[j + half];
        int s1 = csr_src[j + 2 + half];
        int s2 = csr_src[j + 4 + half];
        int s3 = csr_src[j + 6 + half];
        bf16x8 v0 = *(const bf16x8*)&hW[(size_t)s0 * DD + fo];
        bf16x8 v1 = *(const bf16x8*)&hW[(size_t)s1 * DD + fo];
        bf16x8 v2 = *(const bf16x8*)&hW[(size_t)s2 * DD + fo];
        bf16x8 v3 = *(const bf16x8*)&hW[(size_t)s3 * DD + fo];
#pragma unroll
        for (int q = 0; q < 8; q++) acc[q] += (float)v0[q];
#pragma unroll
        for (int q = 0; q < 8; q++) acc[q] += (float)v1[q];
#pragma unroll
        for (int q = 0; q < 8; q++) acc[q] += (float)v2[q];
#pragma unroll
        for (int q = 0; q < 8; q++) acc[q] += (float)v3[q];
    }
    for (; j + half < end; j += 2) {
        int s = csr_src[j + half];
        bf16x8 v = *(const bf16x8*)&hW[(size_t)s * DD + fo];
#pragma unroll
        for (int q = 0; q < 8; q++) acc[q] += (float)v[q];
    }
#pragma unroll
    for (int q = 0; q < 8; q++) acc[q] += __shfl_xor(acc[q], 32, 64);

    if (half == 0) {
        float4 b0 = *(const float4*)&bias[fo];
        float4 b1 = *(const float4*)&bias[fo + 4];
        bf16x8 rv = *(const bf16x8*)&res[(size_t)node * DD + fo];
        bf16x8 o;
        o[0] = (bf16)(fmaxf(acc[0] + b0.x, 0.f) + (float)rv[0]);
        o[1] = (bf16)(fmaxf(acc[1] + b0.y, 0.f) + (float)rv[1]);
        o[2] = (bf16)(fmaxf(acc[2] + b0.z, 0.f) + (float)rv[2]);
        o[3] = (bf16)(fmaxf(acc[3] + b0.w, 0.f) + (float)rv[3]);
        o[4] = (bf16)(fmaxf(acc[4] + b1.x, 0.f) + (float)rv[4]);
        o[5] = (bf16)(fmaxf(acc[5] + b1.y, 0.f) + (float)rv[5]);
        o[6] = (bf16)(fmaxf(acc[6] + b1.z, 0.f) + (float)rv[6]);
        o[7] = (bf16)(fmaxf(acc[7] + b1.w, 0.f) + (float)rv[7]);
        *(bf16x8*)&H[(size_t)node * DD + fo] = o;
    }
}

__global__ __launch_bounds__(256) void predictor_kernel(const float* __restrict__ G1,
                                                        const float* __restrict__ G2,
                                                        const float* __restrict__ Wp,
                                                        const float* __restrict__ bp,
                                                        float* __restrict__ out) {
    int i = blockIdx.x * 256 + threadIdx.x;
    if (i >= NG) return;
    float acc = bp[0];
    for (int f = 0; f < GFEAT; f++)
        acc += (G1[i * GFEAT + f] + G2[i * GFEAT + f]) * Wp[f];
    out[i] = acc;
}

extern "C" void kernel_launch(void* const* d_in, const int* in_sizes, int n_in,
                              void* d_out, int out_size, void* d_ws, size_t ws_size,
                              hipStream_t stream) {
    const float* X1   = (const float*)d_in[0];
    const float* X2   = (const float*)d_in[2];
    const int*   src1 = (const int*)d_in[4];
    const int*   dst1 = (const int*)d_in[5];
    const int*   gid1 = (const int*)d_in[6];
    const int*   src2 = (const int*)d_in[7];
    const int*   dst2 = (const int*)d_in[8];
    const int*   gid2 = (const int*)d_in[9];
    const float* W1  = (const float*)d_in[10]; const float* b1  = (const float*)d_in[11];
    const float* Wr1 = (const float*)d_in[12]; const float* br1 = (const float*)d_in[13];
    const float* W2  = (const float*)d_in[14]; const float* b2  = (const float*)d_in[15];
    const float* Wr2 = (const float*)d_in[16]; const float* br2 = (const float*)d_in[17];
    const float* Ri1 = (const float*)d_in[18]; const float* rbi1 = (const float*)d_in[19];
    const float* Ro1 = (const float*)d_in[20]; const float* rbo1 = (const float*)d_in[21];
    const float* Ri2 = (const float*)d_in[22]; const float* rbi2 = (const float*)d_in[23];
    const float* Ro2 = (const float*)d_in[24]; const float* rbo2 = (const float*)d_in[25];
    const float* Wp  = (const float*)d_in[26]; const float* bp  = (const float*)d_in[27];

    // workspace layout (per-branch buffers; lifetime-disjoint aliases)
    const size_t NB = (size_t)NN * DD * sizeof(bf16);   // 25.6 MB
    char* p = (char*)d_ws;
    bf16* H1   = (bf16*)p; p += NB;     // eb1 (CSR L3/L4), then H (agg->Ri)
    bf16* H2   = (bf16*)p; p += NB;
    bf16* hWR1 = (bf16*)p; p += NB;     // hW (fusedconv->agg), then R (Ri->Ro)
    bf16* hWR2 = (bf16*)p; p += NB;
    bf16* res1 = (bf16*)p; p += NB;     // res (fusedconv->agg)
    bf16* res2 = (bf16*)p; p += NB;
    float* G1  = (float*)p; p += (size_t)NG * GFEAT * sizeof(float);
    float* G2  = (float*)p; p += (size_t)NG * GFEAT * sizeof(float);
    // 8 weight mats; order: W1,Wr1,Ri1,Ro1,W2,Wr2,Ri2,Ro2 (W|Wr contiguous = fused Bt)
    bf16* Wbase = (bf16*)p; p += 8 * 65536 * sizeof(bf16);
    int* offs1 = (int*)p; p += (NN + 1) * sizeof(int);
    int* offs2 = (int*)p; p += (NN + 1) * sizeof(int);
    int* cnt1  = (int*)p; p += NBKT * NCHUNK * sizeof(int);
    int* cnt2  = (int*)p; p += NBKT * NCHUNK * sizeof(int);
    int* csr1  = (int*)p; p += NE * sizeof(int);
    int* csr2  = (int*)p; p += NE * sizeof(int);
    // edge-pair scratch aliases H (dead until agg writes it in L5)
    int2* eb1 = (int2*)H1;
    int2* eb2 = (int2*)H2;

    // L1: zero G | weight convert | coarse hist     (independent roles)
    k_prep<<<1040, 512, 0, stream>>>(G1, G2, W1, Wr1, Ri1, Ro1, W2, Wr2, Ri2, Ro2,
                                     Wbase, dst1, dst2, cnt1, cnt2);
    // L2: scan (tiny)
    csr_scan_kernel<<<dim3(1, 2), 1024, 0, stream>>>(cnt1, cnt2, offs1, offs2);
    // L3: partition || fusedconv part 1
    k_part_gemm<<<512 + NF1, 512, 0, stream>>>(
        src1, src2, dst1, dst2, cnt1, cnt2, eb1, eb2,
        X1, X2, Wbase + 0 * 65536, Wbase + 4 * 65536, br1, br2,
        hWR1, hWR2, res1, res2, NN);
    // L4: bucket sort || fusedconv part 2
    k_sort_gemm<<<256 + NF2, 512, 0, stream>>>(
        cnt1, cnt2, eb1, eb2, offs1, offs2, csr1, csr2,
        X1, X2, Wbase + 0 * 65536, Wbase + 4 * 65536, br1, br2,
        hWR1, hWR2, res1, res2, NN);
    // L5: H = relu(agg + b) + res
    agg_combine2_kernel<<<dim3((NN + 3) / 4, 2), 256, 0, stream>>>(
        hWR1, hWR2, csr1, csr2, offs1, offs2, b1, b2, res1, res2, H1, H2, NN);
    // L6: R = relu(H @ Ri + rbi)
    mfma_gemm2_kernel<<<dim3(25 * 16, 2), 512, 0, stream>>>(
        H1, H2, Wbase + 2 * 65536, Wbase + 6 * 65536, rbi1, rbi2,
        hWR1, hWR2, NN, DD, 1);
    // L7: G = segment_sum(R @ Ro + rbo) fused
    mfma_gemm_reduce2_kernel<<<dim3(25 * 16, 2), 512, 0, stream>>>(
        hWR1, hWR2, Wbase + 3 * 65536, Wbase + 7 * 65536, rbo1, rbo2,
        gid1, gid2, G1, G2, NN, GFEAT);
    // L8: predictor
    predictor_kernel<<<(NG + 255) / 256, 256, 0, stream>>>(G1, G2, Wp, bp, (float*)d_out);
}

// Round 9
// 538.905 us; speedup vs baseline: 1.1557x; 1.1557x over previous
//
#include <hip/hip_runtime.h>

// Problem constants (fixed by reference)
#define NN 50000      // nodes
#define NE 800000     // edges
#define DD 256        // node feat dim
#define GFEAT 200     // graph feat dim
#define NG 512        // graphs

typedef __bf16 bf16;
typedef bf16 bf16x4 __attribute__((ext_vector_type(4)));
typedef bf16 bf16x8 __attribute__((ext_vector_type(8)));
typedef float f32x4 __attribute__((ext_vector_type(4)));

// async global->LDS, 16B per lane. HW dest = wave-uniform base + lane*16.
__device__ __forceinline__ void gl_lds16(const bf16* g, bf16* l) {
    __builtin_amdgcn_global_load_lds(
        (const __attribute__((address_space(1))) uint32_t*)(g),
        (__attribute__((address_space(3))) uint32_t*)(l), 16, 0, 0);
}

// BK=64 LDS tile [R][64]; 16B chunk c holds global chunk c^((row>>1)&7)
__device__ __forceinline__ bf16x8 frag_ld64(const bf16* s, int R, int C) {
    return *(const bf16x8*)&s[R * 64 + ((C ^ ((R >> 1) & 7)) << 3)];
}

#define EPI_STRIDE 136   // bf16 elems; 272 B row stride (16B-aligned, bank-shift 4/row)

// ---------------------------------------------------------------------------
// weight conversion: fp32 [256][N] -> bf16 [n][k] transposed, zero-padded.
// 64x64 LDS-transpose tiles: coalesced reads AND writes.
// grid (8 mats * 16 tiles), 256 threads.
// ---------------------------------------------------------------------------
__global__ __launch_bounds__(256) void conv_w8t_kernel(
    const float* __restrict__ w0, const float* __restrict__ w1,
    const float* __restrict__ w2, const float* __restrict__ w3,
    const float* __restrict__ w4, const float* __restrict__ w5,
    const float* __restrict__ w6, const float* __restrict__ w7,
    bf16* __restrict__ out_base) {
    const float* ws[8] = {w0, w1, w2, w3, w4, w5, w6, w7};
    const int Ns[8] = {DD, DD, DD, GFEAT, DD, DD, DD, GFEAT};
    const int m = blockIdx.x >> 4;
    const int tile = blockIdx.x & 15;
    const int k0 = (tile >> 2) * 64, n0 = (tile & 3) * 64;
    const float* in = ws[m];
    const int N = Ns[m];
    const int t = threadIdx.x;
    __shared__ float ts[64][65];
#pragma unroll
    for (int r = 0; r < 16; r++) {
        int dk = r * 4 + (t >> 6), dn = t & 63;
        int n = n0 + dn;
        ts[dk][dn] = (n < N) ? in[(k0 + dk) * N + n] : 0.f;
    }
    __syncthreads();
#pragma unroll
    for (int r = 0; r < 16; r++) {
        int dn = r * 4 + (t >> 6), dk = t & 63;
        out_base[(size_t)m * 65536 + (size_t)(n0 + dn) * 256 + k0 + dk] = (bf16)ts[dk][dn];
    }
}

__global__ __launch_bounds__(256) void zero_g_kernel(float* __restrict__ G0,
                                                     float* __restrict__ G1) {
    float* G = blockIdx.y ? G1 : G0;
    int i = blockIdx.x * 256 + threadIdx.x;
    if (i < NG * GFEAT) G[i] = 0.f;
}

// ---------------------------------------------------------------------------
// CSR build: two-level counting sort, zero global atomics, O(1) reads/edge.
// ---------------------------------------------------------------------------
#define NBKT   128
#define NPB    391            // ceil(NN / NBKT); 128*391 = 50048
#define NCHUNK 256
#define CE     ((NE + NCHUNK - 1) / NCHUNK)   // 3125 edges per chunk

__global__ __launch_bounds__(256) void csr_coarse_hist_kernel(
    const int* __restrict__ d0, const int* __restrict__ d1,
    int* __restrict__ cnt0, int* __restrict__ cnt1) {
    const int blk = blockIdx.x, t = threadIdx.x;
    const int* dst = blockIdx.y ? d1 : d0;
    int* cnt = blockIdx.y ? cnt1 : cnt0;
    __shared__ int hist[NBKT];
    if (t < NBKT) hist[t] = 0;
    __syncthreads();
    const int e0 = blk * CE;
    const int e1 = (e0 + CE < NE) ? e0 + CE : NE;
    for (int e = e0 + t; e < e1; e += 256)
        atomicAdd(&hist[dst[e] / NPB], 1);
    __syncthreads();
    if (t < NBKT) cnt[t * NCHUNK + blk] = hist[t];   // bucket-major
}

__global__ __launch_bounds__(1024) void csr_scan_kernel(
    int* __restrict__ cnt0, int* __restrict__ cnt1,
    int* __restrict__ offs0, int* __restrict__ offs1) {
    int* cnt = blockIdx.y ? cnt1 : cnt0;
    const int t = threadIdx.x;
    const int PER = (NBKT * NCHUNK) / 1024;   // 32
    int v[PER];
    int sum = 0;
    const int base = t * PER;
#pragma unroll
    for (int i = 0; i < PER; i += 4) {
        int4 q = *(const int4*)&cnt[base + i];
        v[i] = q.x; v[i + 1] = q.y; v[i + 2] = q.z; v[i + 3] = q.w;
        sum += q.x + q.y + q.z + q.w;
    }
    __shared__ int s[1024];
    s[t] = sum;
    __syncthreads();
    for (int off = 1; off < 1024; off <<= 1) {
        int a = (t >= off) ? s[t - off] : 0;
        __syncthreads();
        s[t] += a;
        __syncthreads();
    }
    int run = s[t] - sum;   // exclusive prefix of this thread's chunk
#pragma unroll
    for (int i = 0; i < PER; i++) { int c = v[i]; cnt[base + i] = run; run += c; }
    if (t == 0) (blockIdx.y ? offs1 : offs0)[NN] = NE;
}

__global__ __launch_bounds__(256) void csr_partition_kernel(
    const int* __restrict__ sA, const int* __restrict__ sB,
    const int* __restrict__ d0, const int* __restrict__ d1,
    const int* __restrict__ cnt0, const int* __restrict__ cnt1,
    int2* __restrict__ eb0, int2* __restrict__ eb1) {
    const int blk = blockIdx.x, t = threadIdx.x;
    const int* src = blockIdx.y ? sB : sA;
    const int* dst = blockIdx.y ? d1 : d0;
    const int* cnt = blockIdx.y ? cnt1 : cnt0;
    int2* eb = blockIdx.y ? eb1 : eb0;
    __shared__ int cur[NBKT];
    if (t < NBKT) cur[t] = cnt[t * NCHUNK + blk];   // this chunk's start in each bucket
    __syncthreads();
    const int e0 = blk * CE;
    const int e1 = (e0 + CE < NE) ? e0 + CE : NE;
    for (int e = e0 + t; e < e1; e += 256) {
        int d = dst[e], s = src[e];
        int pos = atomicAdd(&cur[d / NPB], 1);      // LDS atomic, range disjoint per block
        eb[pos] = make_int2(s, d);
    }
}

__global__ __launch_bounds__(512) void csr_bucket_sort_kernel(
    const int* __restrict__ cnt0, const int* __restrict__ cnt1,
    const int2* __restrict__ eb0, const int2* __restrict__ eb1,
    int* __restrict__ offs0, int* __restrict__ offs1,
    int* __restrict__ csr0, int* __restrict__ csr1) {
    const int b = blockIdx.x, t = threadIdx.x;
    const int* cnt = blockIdx.y ? cnt1 : cnt0;
    const int2* eb = blockIdx.y ? eb1 : eb0;
    int* offs = blockIdx.y ? offs1 : offs0;
    int* csr = blockIdx.y ? csr1 : csr0;
    const int lo = b * NPB;
    const int ncnt = (NN - lo < NPB) ? (NN - lo) : NPB;
    const int beg = cnt[b * NCHUNK];
    const int end = (b == NBKT - 1) ? NE : cnt[(b + 1) * NCHUNK];

    __shared__ int hist[NPB];
    __shared__ int s[512];
    if (t < NPB) hist[t] = 0;
    __syncthreads();
    for (int i = beg + t; i < end; i += 512)
        atomicAdd(&hist[eb[i].y - lo], 1);
    __syncthreads();

    int h = (t < NPB) ? hist[t] : 0;
    s[t] = h;
    __syncthreads();
    for (int off = 1; off < 512; off <<= 1) {
        int a = (t >= off) ? s[t - off] : 0;
        __syncthreads();
        s[t] += a;
        __syncthreads();
    }
    int excl = s[t] - h;
    __syncthreads();
    if (t < NPB) hist[t] = excl;                 // local cursors
    if (t < ncnt) offs[lo + t] = beg + excl;     // final global offsets
    __syncthreads();

    for (int i = beg + t; i < end; i += 512) {
        int2 v = eb[i];
        int pos = atomicAdd(&hist[v.y - lo], 1);
        csr[beg + pos] = v.x;                    // contiguous ~25 KB region per block
    }
}

// ---------------------------------------------------------------------------
// 256x128-tile bf16 MFMA GEMM family (R6, best measured), 512 threads (8 waves
// = 4 row x 2 col), BK=64, K=256, both branches via blockIdx.y, XCD-swizzled
// block decode. LDS: As 256x64 (32KB) | Bs 128x64 (16KB).
// ---------------------------------------------------------------------------
__global__ __launch_bounds__(512) void mfma_gemm2_kernel(
    const bf16* __restrict__ A0, const bf16* __restrict__ A1,
    const bf16* __restrict__ Bt0, const bf16* __restrict__ Bt1,
    const float* __restrict__ bias0, const float* __restrict__ bias1,
    bf16* __restrict__ out0, bf16* __restrict__ out1,
    int M, int Nb, int do_relu) {
    const int lid = blockIdx.x;
    const int r8 = lid & 7, cc = (lid >> 3) & 1, g = lid >> 4;
    const int row_blk = g * 8 + r8;
    if (row_blk * 256 >= M) return;
    const bf16* A = blockIdx.y ? A1 : A0;
    const bf16* Bt = blockIdx.y ? Bt1 : Bt0;
    const float* bias = blockIdx.y ? bias1 : bias0;
    bf16* out = blockIdx.y ? out1 : out0;

    __shared__ bf16 smem[24576];       // As 16384 | Bs 8192
    bf16* As = smem;
    bf16* Bs = smem + 16384;

    const int t    = threadIdx.x;
    const int lane = t & 63;
    const int w    = t >> 6;
    const int row0 = row_blk * 256;
    const int col0 = cc * 128;

    f32x4 acc[4][4] = {};
    const int wm = (w >> 1) * 64, wn = (w & 1) * 64;
    const int fm = lane & 15, fC = lane >> 4;

    for (int k0 = 0; k0 < 256; k0 += 64) {
#pragma unroll
        for (int r = 0; r < 4; r++) {            // As: 2048 chunks
            int flat = r * 512 + t;
            int fr = flat >> 3, fc = flat & 7;
            int fcg = fc ^ ((fr >> 1) & 7);
            int arow = row0 + fr;
            if (arow > M - 1) arow = M - 1;
            gl_lds16(&A[(size_t)arow * 256 + k0 + fcg * 8], &As[flat * 8]);
        }
#pragma unroll
        for (int r = 0; r < 2; r++) {            // Bs: 1024 chunks
            int flat = r * 512 + t;
            int fr = flat >> 3, fc = flat & 7;
            int fcg = fc ^ ((fr >> 1) & 7);
            int brow = col0 + fr;                // Bt padded to 256 rows
            gl_lds16(&Bt[(size_t)brow * 256 + k0 + fcg * 8], &Bs[flat * 8]);
        }
        __syncthreads();
#pragma unroll
        for (int s = 0; s < 2; s++) {
            bf16x8 af[4], bfr[4];
#pragma unroll
            for (int i = 0; i < 4; i++) af[i] = frag_ld64(As, wm + i * 16 + fm, s * 4 + fC);
#pragma unroll
            for (int i = 0; i < 4; i++) bfr[i] = frag_ld64(Bs, wn + i * 16 + fm, s * 4 + fC);
#pragma unroll
            for (int i = 0; i < 4; i++)
#pragma unroll
                for (int j = 0; j < 4; j++)
                    acc[i][j] = __builtin_amdgcn_mfma_f32_16x16x32_bf16(af[i], bfr[j], acc[i][j], 0, 0, 0);
        }
        __syncthreads();
    }

    float bv[4];
#pragma unroll
    for (int j = 0; j < 4; j++) {
        int col = col0 + wn + fm + j * 16;
        bv[j] = (col < Nb) ? bias[col] : 0.f;
    }

#pragma unroll
    for (int p = 0; p < 4; p++) {                // 4 passes of 64 rows
        if ((w >> 1) == p) {
#pragma unroll
            for (int i = 0; i < 4; i++)
#pragma unroll
                for (int j = 0; j < 4; j++)
#pragma unroll
                    for (int r2 = 0; r2 < 4; r2++) {
                        int rl = i * 16 + (lane >> 4) * 4 + r2;   // 0..63
                        int cl = wn + fm + j * 16;                // 0..127
                        float v = acc[i][j][r2] + bv[j];
                        if (do_relu) v = fmaxf(v, 0.f);
                        smem[rl * EPI_STRIDE + cl] = (bf16)v;
                    }
        }
        __syncthreads();
#pragma unroll
        for (int q = 0; q < 2; q++) {            // 1024 slots of 8 bf16
            int flat = q * 512 + t;
            int rl = flat >> 4, seg = flat & 15;
            int grow = row0 + p * 64 + rl;
            if (grow < M)
                *(bf16x8*)&out[(size_t)grow * 256 + col0 + seg * 8] =
                    *(const bf16x8*)&smem[rl * EPI_STRIDE + seg * 8];
        }
        __syncthreads();
    }
}

// Fused conv + W|Wr GEMM: A is fp32 X (converted during reg-staged A load).
// Bt2 512x256: cols 0-255 -> out_lo (no act), 256-511 -> out_hi=relu(.+bias_hi).
// grid (25*32, 2): r8=lid&7, cc=(lid>>3)&3, g=lid>>5.
__global__ __launch_bounds__(512) void mfma_gemm_fusedconv2_kernel(
    const float* __restrict__ X0, const float* __restrict__ X1,
    const bf16* __restrict__ Bt2_0, const bf16* __restrict__ Bt2_1,
    const float* __restrict__ bh0, const float* __restrict__ bh1,
    bf16* __restrict__ lo0, bf16* __restrict__ lo1,
    bf16* __restrict__ hi0, bf16* __restrict__ hi1, int M) {
    const int lid = blockIdx.x;
    const int r8 = lid & 7, cc = (lid >> 3) & 3, g = lid >> 5;
    const int row_blk = g * 8 + r8;
    if (row_blk * 256 >= M) return;
    const float* Xf = blockIdx.y ? X1 : X0;
    const bf16* Bt2 = blockIdx.y ? Bt2_1 : Bt2_0;
    const float* bias_hi = blockIdx.y ? bh1 : bh0;
    bf16* out_lo = blockIdx.y ? lo1 : lo0;
    bf16* out_hi = blockIdx.y ? hi1 : hi0;

    __shared__ bf16 smem[24576];
    bf16* As = smem;
    bf16* Bs = smem + 16384;

    const int t    = threadIdx.x;
    const int lane = t & 63;
    const int w    = t >> 6;
    const int row0 = row_blk * 256;
    const int col0 = cc * 128;   // 0..384

    f32x4 acc[4][4] = {};
    const int wm = (w >> 1) * 64, wn = (w & 1) * 64;
    const int fm = lane & 15, fC = lane >> 4;

    for (int k0 = 0; k0 < 256; k0 += 64) {
#pragma unroll
        for (int r = 0; r < 2; r++) {            // Bs async first
            int flat = r * 512 + t;
            int fr = flat >> 3, fc = flat & 7;
            int fcg = fc ^ ((fr >> 1) & 7);
            int brow = col0 + fr;
            gl_lds16(&Bt2[(size_t)brow * 256 + k0 + fcg * 8], &Bs[flat * 8]);
        }
#pragma unroll
        for (int r = 0; r < 4; r++) {            // As: fp32 load + cvt + swizzled write
            int flat = r * 512 + t;
            int fr = flat >> 3, fc = flat & 7;
            int arow = row0 + fr;
            if (arow > M - 1) arow = M - 1;
            const float* gsrc = &Xf[(size_t)arow * 256 + k0 + fc * 8];
            float4 u0 = *(const float4*)gsrc;
            float4 u1 = *(const float4*)(gsrc + 4);
            bf16x8 o;
            o[0] = (bf16)u0.x; o[1] = (bf16)u0.y; o[2] = (bf16)u0.z; o[3] = (bf16)u0.w;
            o[4] = (bf16)u1.x; o[5] = (bf16)u1.y; o[6] = (bf16)u1.z; o[7] = (bf16)u1.w;
            *(bf16x8*)&As[fr * 64 + ((fc ^ ((fr >> 1) & 7)) << 3)] = o;
        }
        __syncthreads();
#pragma unroll
        for (int s = 0; s < 2; s++) {
            bf16x8 af[4], bfr[4];
#pragma unroll
            for (int i = 0; i < 4; i++) af[i] = frag_ld64(As, wm + i * 16 + fm, s * 4 + fC);
#pragma unroll
            for (int i = 0; i < 4; i++) bfr[i] = frag_ld64(Bs, wn + i * 16 + fm, s * 4 + fC);
#pragma unroll
            for (int i = 0; i < 4; i++)
#pragma unroll
                for (int j = 0; j < 4; j++)
                    acc[i][j] = __builtin_amdgcn_mfma_f32_16x16x32_bf16(af[i], bfr[j], acc[i][j], 0, 0, 0);
        }
        __syncthreads();
    }

    const bool hi = (col0 >= 256);          // block-uniform
    bf16* out = hi ? out_hi : out_lo;
    const int cb = hi ? col0 - 256 : col0;

    float bv[4];
#pragma unroll
    for (int j = 0; j < 4; j++) {
        int col = cb + wn + fm + j * 16;
        bv[j] = hi ? bias_hi[col] : 0.f;
    }

#pragma unroll
    for (int p = 0; p < 4; p++) {
        if ((w >> 1) == p) {
#pragma unroll
            for (int i = 0; i < 4; i++)
#pragma unroll
                for (int j = 0; j < 4; j++)
#pragma unroll
                    for (int r2 = 0; r2 < 4; r2++) {
                        int rl = i * 16 + (lane >> 4) * 4 + r2;
                        int cl = wn + fm + j * 16;
                        float v = acc[i][j][r2] + bv[j];
                        if (hi) v = fmaxf(v, 0.f);
                        smem[rl * EPI_STRIDE + cl] = (bf16)v;
                    }
        }
        __syncthreads();
#pragma unroll
        for (int q = 0; q < 2; q++) {
            int flat = q * 512 + t;
            int rl = flat >> 4, seg = flat & 15;
            int grow = row0 + p * 64 + rl;
            if (grow < M)
                *(bf16x8*)&out[(size_t)grow * 256 + cb + seg * 8] =
                    *(const bf16x8*)&smem[rl * EPI_STRIDE + seg * 8];
        }
        __syncthreads();
    }
}

// Ro GEMM + per-graph segment reduce fused. P-tile -> LDS; per-column fp32
// segment sums over sorted gids atomicAdd'ed into G. grid (25*16, 2).
__global__ __launch_bounds__(512) void mfma_gemm_reduce2_kernel(
    const bf16* __restrict__ A0, const bf16* __restrict__ A1,
    const bf16* __restrict__ Bt0, const bf16* __restrict__ Bt1,
    const float* __restrict__ bias0, const float* __restrict__ bias1,
    const int* __restrict__ gid0, const int* __restrict__ gid1,
    float* __restrict__ G0, float* __restrict__ G1, int M, int Nb) {
    const int lid = blockIdx.x;
    const int r8 = lid & 7, cc = (lid >> 3) & 1, g = lid >> 4;
    const int row_blk = g * 8 + r8;
    if (row_blk * 256 >= M) return;
    const bf16* A = blockIdx.y ? A1 : A0;
    const bf16* Bt = blockIdx.y ? Bt1 : Bt0;
    const float* bias = blockIdx.y ? bias1 : bias0;
    const int* gids = blockIdx.y ? gid1 : gid0;
    float* G = blockIdx.y ? G1 : G0;

    __shared__ bf16 smem[24576];
    bf16* As = smem;
    bf16* Bs = smem + 16384;

    const int t    = threadIdx.x;
    const int lane = t & 63;
    const int w    = t >> 6;
    const int row0 = row_blk * 256;
    const int col0 = cc * 128;

    f32x4 acc[4][4] = {};
    const int wm = (w >> 1) * 64, wn = (w & 1) * 64;
    const int fm = lane & 15, fC = lane >> 4;

    for (int k0 = 0; k0 < 256; k0 += 64) {
#pragma unroll
        for (int r = 0; r < 4; r++) {
            int flat = r * 512 + t;
            int fr = flat >> 3, fc = flat & 7;
            int fcg = fc ^ ((fr >> 1) & 7);
            int arow = row0 + fr;
            if (arow > M - 1) arow = M - 1;
            gl_lds16(&A[(size_t)arow * 256 + k0 + fcg * 8], &As[flat * 8]);
        }
#pragma unroll
        for (int r = 0; r < 2; r++) {
            int flat = r * 512 + t;
            int fr = flat >> 3, fc = flat & 7;
            int fcg = fc ^ ((fr >> 1) & 7);
            int brow = col0 + fr;
            gl_lds16(&Bt[(size_t)brow * 256 + k0 + fcg * 8], &Bs[flat * 8]);
        }
        __syncthreads();
#pragma unroll
        for (int s = 0; s < 2; s++) {
            bf16x8 af[4], bfr[4];
#pragma unroll
            for (int i = 0; i < 4; i++) af[i] = frag_ld64(As, wm + i * 16 + fm, s * 4 + fC);
#pragma unroll
            for (int i = 0; i < 4; i++) bfr[i] = frag_ld64(Bs, wn + i * 16 + fm, s * 4 + fC);
#pragma unroll
            for (int i = 0; i < 4; i++)
#pragma unroll
                for (int j = 0; j < 4; j++)
                    acc[i][j] = __builtin_amdgcn_mfma_f32_16x16x32_bf16(af[i], bfr[j], acc[i][j], 0, 0, 0);
        }
        __syncthreads();
    }

    float bv[4];
#pragma unroll
    for (int j = 0; j < 4; j++) {
        int col = col0 + wn + fm + j * 16;
        bv[j] = (col < Nb) ? bias[col] : 0.f;
    }

#pragma unroll
    for (int p = 0; p < 4; p++) {
        if ((w >> 1) == p) {
#pragma unroll
            for (int i = 0; i < 4; i++)
#pragma unroll
                for (int j = 0; j < 4; j++)
#pragma unroll
                    for (int r2 = 0; r2 < 4; r2++) {
                        int rl = i * 16 + (lane >> 4) * 4 + r2;
                        int cl = wn + fm + j * 16;
                        smem[rl * EPI_STRIDE + cl] = (bf16)(acc[i][j][r2] + bv[j]);
                    }
        }
        __syncthreads();
        // segment reduce: 4 threads per column, 16 rows each; sorted gids ->
        // flush partial into G on boundary (fp32 atomic, device scope).
        {
            int c = t & 127, rh = t >> 7;        // rh 0..3
            int colg = col0 + c;
            if (colg < Nb) {
                float run = 0.f;
                int gprev = -1;
                for (int r = 0; r < 16; r++) {
                    int grow = row0 + p * 64 + rh * 16 + r;
                    if (grow >= M) break;
                    int gg = gids[grow];
                    if (gg != gprev) {
                        if (gprev >= 0) atomicAdd(&G[(size_t)gprev * GFEAT + colg], run);
                        run = 0.f;
                        gprev = gg;
                    }
                    run += (float)smem[(rh * 16 + r) * EPI_STRIDE + c];
                }
                if (gprev >= 0) atomicAdd(&G[(size_t)gprev * GFEAT + colg], run);
            }
        }
        __syncthreads();
    }
}

// ---------------------------------------------------------------------------
// edge aggregation + combine, XCD-PARTITIONED BY BRANCH:
// 1D grid 25000 blocks; xcd = blockIdx.x & 7 (round-robin dispatch heuristic).
// XCDs 0-3 -> branch 0, XCDs 4-7 -> branch 1: each XCD's L2 streams only ONE
// branch's 25.6 MB hW table (was both = 51.2 MB -> FETCH 377 MB ~ 8*51.2).
// Mapping is perf-only; correctness independent of XCD assignment.
// ---------------------------------------------------------------------------
__global__ __launch_bounds__(256) void agg_combine2_kernel(
    const bf16* __restrict__ hW0, const bf16* __restrict__ hW1,
    const int* __restrict__ csr0, const int* __restrict__ csr1,
    const int* __restrict__ offs0, const int* __restrict__ offs1,
    const float* __restrict__ bias0, const float* __restrict__ bias1,
    const bf16* __restrict__ res0, const bf16* __restrict__ res1,
    bf16* __restrict__ H0, bf16* __restrict__ H1, int n_nodes) {
    const int x = blockIdx.x;
    const int xcd = x & 7;
    const int branch = xcd >> 2;               // XCD 0-3: br0, 4-7: br1
    const int local_blk = (x >> 3) * 4 + (xcd & 3);   // 0..12499 within branch

    const bf16* hW = branch ? hW1 : hW0;
    const int* csr_src = branch ? csr1 : csr0;
    const int* offsets = branch ? offs1 : offs0;
    const float* bias = branch ? bias1 : bias0;
    const bf16* res = branch ? res1 : res0;
    bf16* H = branch ? H1 : H0;

    int wave = threadIdx.x >> 6;
    int lane = threadIdx.x & 63;
    int node = local_blk * 4 + wave;
    if (node >= n_nodes) return;
    int beg = offsets[node], end = offsets[node + 1];
    const int half = lane >> 5;
    const int fo   = (lane & 31) * 8;

    float acc[8] = {};
    int j = beg;
    for (; j + 6 + half < end; j += 8) {
        int s0 = csr_src[j + half];
        int s1 = csr_src[j + 2 + half];
        int s2 = csr_src[j + 4 + half];
        int s3 = csr_src[j + 6 + half];
        bf16x8 v0 = *(const bf16x8*)&hW[(size_t)s0 * DD + fo];
        bf16x8 v1 = *(const bf16x8*)&hW[(size_t)s1 * DD + fo];
        bf16x8 v2 = *(const bf16x8*)&hW[(size_t)s2 * DD + fo];
        bf16x8 v3 = *(const bf16x8*)&hW[(size_t)s3 * DD + fo];
#pragma unroll
        for (int q = 0; q < 8; q++) acc[q] += (float)v0[q];
#pragma unroll
        for (int q = 0; q < 8; q++) acc[q] += (float)v1[q];
#pragma unroll
        for (int q = 0; q < 8; q++) acc[q] += (float)v2[q];
#pragma unroll
        for (int q = 0; q < 8; q++) acc[q] += (float)v3[q];
    }
    for (; j + half < end; j += 2) {
        int s = csr_src[j + half];
        bf16x8 v = *(const bf16x8*)&hW[(size_t)s * DD + fo];
#pragma unroll
        for (int q = 0; q < 8; q++) acc[q] += (float)v[q];
    }
#pragma unroll
    for (int q = 0; q < 8; q++) acc[q] += __shfl_xor(acc[q], 32, 64);

    if (half == 0) {
        float4 b0 = *(const float4*)&bias[fo];
        float4 b1 = *(const float4*)&bias[fo + 4];
        bf16x8 rv = *(const bf16x8*)&res[(size_t)node * DD + fo];
        bf16x8 o;
        o[0] = (bf16)(fmaxf(acc[0] + b0.x, 0.f) + (float)rv[0]);
        o[1] = (bf16)(fmaxf(acc[1] + b0.y, 0.f) + (float)rv[1]);
        o[2] = (bf16)(fmaxf(acc[2] + b0.z, 0.f) + (float)rv[2]);
        o[3] = (bf16)(fmaxf(acc[3] + b0.w, 0.f) + (float)rv[3]);
        o[4] = (bf16)(fmaxf(acc[4] + b1.x, 0.f) + (float)rv[4]);
        o[5] = (bf16)(fmaxf(acc[5] + b1.y, 0.f) + (float)rv[5]);
        o[6] = (bf16)(fmaxf(acc[6] + b1.z, 0.f) + (float)rv[6]);
        o[7] = (bf16)(fmaxf(acc[7] + b1.w, 0.f) + (float)rv[7]);
        *(bf16x8*)&H[(size_t)node * DD + fo] = o;
    }
}

__global__ __launch_bounds__(256) void predictor_kernel(const float* __restrict__ G1,
                                                        const float* __restrict__ G2,
                                                        const float* __restrict__ Wp,
                                                        const float* __restrict__ bp,
                                                        float* __restrict__ out) {
    int i = blockIdx.x * 256 + threadIdx.x;
    if (i >= NG) return;
    float acc = bp[0];
    for (int f = 0; f < GFEAT; f++)
        acc += (G1[i * GFEAT + f] + G2[i * GFEAT + f]) * Wp[f];
    out[i] = acc;
}

extern "C" void kernel_launch(void* const* d_in, const int* in_sizes, int n_in,
                              void* d_out, int out_size, void* d_ws, size_t ws_size,
                              hipStream_t stream) {
    const float* X1   = (const float*)d_in[0];
    const float* X2   = (const float*)d_in[2];
    const int*   src1 = (const int*)d_in[4];
    const int*   dst1 = (const int*)d_in[5];
    const int*   gid1 = (const int*)d_in[6];
    const int*   src2 = (const int*)d_in[7];
    const int*   dst2 = (const int*)d_in[8];
    const int*   gid2 = (const int*)d_in[9];
    const float* W1  = (const float*)d_in[10]; const float* b1  = (const float*)d_in[11];
    const float* Wr1 = (const float*)d_in[12]; const float* br1 = (const float*)d_in[13];
    const float* W2  = (const float*)d_in[14]; const float* b2  = (const float*)d_in[15];
    const float* Wr2 = (const float*)d_in[16]; const float* br2 = (const float*)d_in[17];
    const float* Ri1 = (const float*)d_in[18]; const float* rbi1 = (const float*)d_in[19];
    const float* Ro1 = (const float*)d_in[20]; const float* rbo1 = (const float*)d_in[21];
    const float* Ri2 = (const float*)d_in[22]; const float* rbi2 = (const float*)d_in[23];
    const float* Ro2 = (const float*)d_in[24]; const float* rbo2 = (const float*)d_in[25];
    const float* Wp  = (const float*)d_in[26]; const float* bp  = (const float*)d_in[27];

    // workspace layout (per-branch buffers; lifetime-disjoint aliases)
    const size_t NB = (size_t)NN * DD * sizeof(bf16);   // 25.6 MB
    char* p = (char*)d_ws;
    bf16* H1   = (bf16*)p; p += NB;     // H (agg->Ri)
    bf16* H2   = (bf16*)p; p += NB;
    bf16* hWR1 = (bf16*)p; p += NB;     // eb1 (CSR), then hW (fusedconv->agg), then R (Ri->Ro)
    bf16* hWR2 = (bf16*)p; p += NB;
    bf16* res1 = (bf16*)p; p += NB;     // res (fusedconv->agg)
    bf16* res2 = (bf16*)p; p += NB;
    float* G1  = (float*)p; p += (size_t)NG * GFEAT * sizeof(float);
    float* G2  = (float*)p; p += (size_t)NG * GFEAT * sizeof(float);
    // 8 weight mats; order: W1,Wr1,Ri1,Ro1,W2,Wr2,Ri2,Ro2 (W|Wr contiguous = fused Bt)
    bf16* Wbase = (bf16*)p; p += 8 * 65536 * sizeof(bf16);
    int* offs1 = (int*)p; p += (NN + 1) * sizeof(int);
    int* offs2 = (int*)p; p += (NN + 1) * sizeof(int);
    int* cnt1  = (int*)p; p += NBKT * NCHUNK * sizeof(int);
    int* cnt2  = (int*)p; p += NBKT * NCHUNK * sizeof(int);
    int* csr1  = (int*)p; p += NE * sizeof(int);
    int* csr2  = (int*)p; p += NE * sizeof(int);
    int2* eb1 = (int2*)hWR1;   // live only during CSR build (before fusedconv writes hW)
    int2* eb2 = (int2*)hWR2;

    zero_g_kernel<<<dim3((NG * GFEAT + 255) / 256, 2), 256, 0, stream>>>(G1, G2);
    conv_w8t_kernel<<<128, 256, 0, stream>>>(W1, Wr1, Ri1, Ro1, W2, Wr2, Ri2, Ro2, Wbase);

    // CSR build (both branches): two-level counting sort, no global atomics
    csr_coarse_hist_kernel<<<dim3(NCHUNK, 2), 256, 0, stream>>>(dst1, dst2, cnt1, cnt2);
    csr_scan_kernel<<<dim3(1, 2), 1024, 0, stream>>>(cnt1, cnt2, offs1, offs2);
    csr_partition_kernel<<<dim3(NCHUNK, 2), 256, 0, stream>>>(
        src1, src2, dst1, dst2, cnt1, cnt2, eb1, eb2);
    csr_bucket_sort_kernel<<<dim3(NBKT, 2), 512, 0, stream>>>(
        cnt1, cnt2, eb1, eb2, offs1, offs2, csr1, csr2);

    // hW = X @ W ; res = relu(X @ Wr + br)   [conv fused into A-staging]
    mfma_gemm_fusedconv2_kernel<<<dim3(25 * 32, 2), 512, 0, stream>>>(
        X1, X2, Wbase + 0 * 65536, Wbase + 4 * 65536, br1, br2,
        hWR1, hWR2, res1, res2, NN);
    // H = relu(agg + b) + res   [XCD-partitioned by branch: 25000 1D blocks]
    agg_combine2_kernel<<<25000, 256, 0, stream>>>(
        hWR1, hWR2, csr1, csr2, offs1, offs2, b1, b2, res1, res2, H1, H2, NN);
    // R = relu(H @ Ri + rbi)
    mfma_gemm2_kernel<<<dim3(25 * 16, 2), 512, 0, stream>>>(
        H1, H2, Wbase + 2 * 65536, Wbase + 6 * 65536, rbi1, rbi2,
        hWR1, hWR2, NN, DD, 1);
    // G = segment_sum(R @ Ro + rbo) fused
    mfma_gemm_reduce2_kernel<<<dim3(25 * 16, 2), 512, 0, stream>>>(
        hWR1, hWR2, Wbase + 3 * 65536, Wbase + 7 * 65536, rbo1, rbo2,
        gid1, gid2, G1, G2, NN, GFEAT);

    predictor_kernel<<<(NG + 255) / 256, 256, 0, stream>>>(G1, G2, Wp, bp, (float*)d_out);
}